// Round 1
// baseline (1093.833 us; speedup 1.0000x reference)
//
#include <hip/hip_runtime.h>
#include <math.h>

// ---------------------------------------------------------------------------
// TensorFieldNetwork on MI355X.
// Core trick: rad_i(a,b) = (relu(rbf(d_ab)@Rw1[i]+Rb1[i])@Rw2[i]+Rb2[i]) depends
// ONLY on the scalar distance d_ab. Tabulate all 12 radial nets on an M-point
// distance grid once per call, then every pair contraction becomes a lerped
// table lookup. This removes the 2.3e11-FLOP per-pair GEMM entirely.
// ---------------------------------------------------------------------------

constexpr int   N_   = 768;
constexpr int   C_   = 128;
constexpr int   M_   = 2048;           // distance-table resolution
constexpr float DMAX_      = 32.0f;    // max pair distance covered (actual max ~18)
constexpr float DELTA_     = DMAX_ / (M_ - 1);
constexpr float INV_DELTA_ = (M_ - 1) / DMAX_;
constexpr float GAMMA_     = 1.6f;     // RBF / (HIGH - LOW)

// table layout: table[(m*12 + filter)*C_ + f]
// workspace layout (floats):
//   table : M_*12*C_            = 3,145,728
//   e     : N_*C_               =    98,304
//   x0a   : N_*C_
//   x1a   : N_*3*C_  (internal layout [N][3][C] for coalesced reads)
//   x0b   : N_*C_
//   x1b   : N_*3*C_
// total ~16.1 MB

// ---------------------------------------------------------------------------
// Kernel A: build the 12 radial-net distance tables.
// grid = M_/8 blocks, 128 threads. Each block handles 8 consecutive m values
// so the Rw2 reads (12*64KB) are amortized 8x.
// ---------------------------------------------------------------------------
__global__ __launch_bounds__(128) void build_table_kernel(
    const float* __restrict__ Rw1, const float* __restrict__ Rb1,
    const float* __restrict__ Rw2, const float* __restrict__ Rb2,
    float* __restrict__ table)
{
    const int f  = threadIdx.x;
    const int m0 = blockIdx.x * 8;

    __shared__ float hs[8][C_];

    // per-m rbf features (uniform across threads; cheap)
    float rbf[8][4];
    const float cent[4] = {0.0f, 2.5f / 3.0f, 5.0f / 3.0f, 2.5f};
#pragma unroll
    for (int mm = 0; mm < 8; ++mm) {
        const float d = (float)(m0 + mm) * DELTA_;
#pragma unroll
        for (int k = 0; k < 4; ++k) {
            const float t = d - cent[k];
            rbf[mm][k] = expf(-GAMMA_ * t * t);
        }
    }

    for (int i = 0; i < 12; ++i) {
        float w1v[4];
#pragma unroll
        for (int k = 0; k < 4; ++k) w1v[k] = Rw1[(i * 4 + k) * C_ + f];
        const float b1v = Rb1[i * C_ + f];

        __syncthreads();   // protect hs from previous iteration's readers
#pragma unroll
        for (int mm = 0; mm < 8; ++mm) {
            float acc = b1v;
#pragma unroll
            for (int k = 0; k < 4; ++k) acc = fmaf(rbf[mm][k], w1v[k], acc);
            hs[mm][f] = fmaxf(acc, 0.0f);
        }
        __syncthreads();

        const float b2v = Rb2[i * C_ + f];
        float out[8];
#pragma unroll
        for (int mm = 0; mm < 8; ++mm) out[mm] = b2v;

        for (int c = 0; c < C_; ++c) {
            const float w = Rw2[(i * C_ + c) * C_ + f];
#pragma unroll
            for (int mm = 0; mm < 8; ++mm) out[mm] = fmaf(hs[mm][c], w, out[mm]);
        }
#pragma unroll
        for (int mm = 0; mm < 8; ++mm)
            table[((size_t)(m0 + mm) * 12 + i) * C_ + f] = out[mm];
    }
}

// ---------------------------------------------------------------------------
// Kernel B: atom-type embedding  e[b,f] = one_hot[b,:] @ embed_W[f,:] + embed_b[f]
// ---------------------------------------------------------------------------
__global__ __launch_bounds__(256) void embed_kernel(
    const float* __restrict__ onehot, const float* __restrict__ eW,
    const float* __restrict__ eb, float* __restrict__ e)
{
    const int idx = blockIdx.x * 256 + threadIdx.x;   // N_*C_ total
    const int b = idx >> 7, f = idx & 127;
    float acc = eb[f];
#pragma unroll
    for (int t = 0; t < 8; ++t) acc = fmaf(onehot[b * 8 + t], eW[f * 8 + t], acc);
    e[idx] = acc;
}

// ---------------------------------------------------------------------------
// Kernel C: layer 0.  One block per atom a; 256 threads = channel f x b-half.
// c00[f] = sum_b T0(d)[f] e[b,f];  c01[f,i] = sum_b T1(d)[f] u_i e[b,f]
// then self-interaction + ELU / norm-gating.
// ---------------------------------------------------------------------------
__global__ __launch_bounds__(256) void layer0_kernel(
    const float* __restrict__ r, const float* __restrict__ e,
    const float* __restrict__ table,
    const float* __restrict__ w0, const float* __restrict__ b0v,
    const float* __restrict__ w1, const float* __restrict__ nlb,
    float* __restrict__ x0_out, float* __restrict__ x1_out)
{
    const int a = blockIdx.x, tid = threadIdx.x;
    const int f = tid & 127, half = tid >> 7;

    __shared__ float rs[N_ * 3];
    for (int i = tid; i < N_ * 3; i += 256) rs[i] = r[i];
    __syncthreads();

    const float rax = rs[a * 3 + 0], ray = rs[a * 3 + 1], raz = rs[a * 3 + 2];

    float c00 = 0.f, cx = 0.f, cy = 0.f, cz = 0.f;
    const int bBeg = half * (N_ / 2), bEnd = bBeg + (N_ / 2);
    for (int b = bBeg; b < bEnd; ++b) {
        const float dx = rax - rs[b * 3 + 0];
        const float dy = ray - rs[b * 3 + 1];
        const float dz = raz - rs[b * 3 + 2];
        const float d2 = fmaf(dx, dx, fmaf(dy, dy, dz * dz));
        const float d  = sqrtf(fmaxf(d2, 1e-12f));
        const float inv = 1.0f / (d + 1e-8f);
        const float ux = dx * inv, uy = dy * inv, uz = dz * inv;

        const float t = d * INV_DELTA_;
        int q = (int)t; q = q > M_ - 2 ? M_ - 2 : q;
        float fr = t - (float)q; fr = fminf(fr, 1.0f);

        const float* tl = table + ((size_t)q * 12) * C_ + f;
        const float* th = tl + 12 * C_;
        const float t0 = fmaf(fr, th[0]  - tl[0],  tl[0]);
        const float t1 = fmaf(fr, th[C_] - tl[C_], tl[C_]);

        const float eb_ = e[b * C_ + f];
        c00 = fmaf(t0, eb_, c00);
        const float te = t1 * eb_;
        cx = fmaf(te, ux, cx); cy = fmaf(te, uy, cy); cz = fmaf(te, uz, cz);
    }

    __shared__ float s[4][2][C_];
    s[0][half][f] = c00; s[1][half][f] = cx; s[2][half][f] = cy; s[3][half][f] = cz;
    __syncthreads();

    if (tid < 128) {
        float y0 = b0v[f], yx = 0.f, yy = 0.f, yz = 0.f;
        const float* w0r = w0 + (size_t)f * C_;
        const float* w1r = w1 + (size_t)f * C_;
        for (int c = 0; c < C_; ++c) {
            const float v0 = s[0][0][c] + s[0][1][c];
            const float v1 = s[1][0][c] + s[1][1][c];
            const float v2 = s[2][0][c] + s[2][1][c];
            const float v3 = s[3][0][c] + s[3][1][c];
            const float a0w = w0r[c], a1w = w1r[c];
            y0 = fmaf(a0w, v0, y0);
            yx = fmaf(a1w, v1, yx); yy = fmaf(a1w, v2, yy); yz = fmaf(a1w, v3, yz);
        }
        const float x0v = y0 > 0.f ? y0 : expm1f(y0);
        const float nsq = fmaf(yx, yx, fmaf(yy, yy, yz * yz));
        const float nn  = sqrtf(fmaxf(nsq, 1e-12f));
        const float g   = nlb[f] + nn;
        const float sc  = (g > 0.f ? g : expm1f(g)) / nn;
        x0_out[a * C_ + f] = x0v;
        x1_out[(a * 3 + 0) * C_ + f] = yx * sc;
        x1_out[(a * 3 + 1) * C_ + f] = yy * sc;
        x1_out[(a * 3 + 2) * C_ + f] = yz * sc;
    }
}

// ---------------------------------------------------------------------------
// Kernel D: full layer (ri = 2 or 7). One block per atom; 256 threads.
// Accumulators per (f): a0, b1[3], a1[3], o0, o1[3]  (11 values)
// ---------------------------------------------------------------------------
template <bool NONLIN, bool LAST>
__global__ __launch_bounds__(256) void full_layer_kernel(
    const float* __restrict__ r,
    const float* __restrict__ x0_in, const float* __restrict__ x1_in,
    const float* __restrict__ table, int ri,
    const float* __restrict__ w0, const float* __restrict__ b0v,
    const float* __restrict__ w1, const float* __restrict__ nlb,
    float* __restrict__ x0_out, float* __restrict__ x1_out,
    float* __restrict__ out, const float* __restrict__ predW,
    const float* __restrict__ predb)
{
    const int a = blockIdx.x, tid = threadIdx.x;
    const int f = tid & 127, half = tid >> 7;

    __shared__ float rs[N_ * 3];
    for (int i = tid; i < N_ * 3; i += 256) rs[i] = r[i];
    __syncthreads();

    const float rax = rs[a * 3 + 0], ray = rs[a * 3 + 1], raz = rs[a * 3 + 2];

    float a0 = 0.f, b1x = 0.f, b1y = 0.f, b1z = 0.f;
    float a1x = 0.f, a1y = 0.f, a1z = 0.f;
    float o0 = 0.f, o1x = 0.f, o1y = 0.f, o1z = 0.f;

    const int bBeg = half * (N_ / 2), bEnd = bBeg + (N_ / 2);
    for (int b = bBeg; b < bEnd; ++b) {
        const float dx = rax - rs[b * 3 + 0];
        const float dy = ray - rs[b * 3 + 1];
        const float dz = raz - rs[b * 3 + 2];
        const float d2 = fmaf(dx, dx, fmaf(dy, dy, dz * dz));
        const float d  = sqrtf(fmaxf(d2, 1e-12f));
        const float inv = 1.0f / (d + 1e-8f);
        const float ux = dx * inv, uy = dy * inv, uz = dz * inv;

        const float t = d * INV_DELTA_;
        int q = (int)t; q = q > M_ - 2 ? M_ - 2 : q;
        float fr = t - (float)q; fr = fminf(fr, 1.0f);

        const float* tl = table + ((size_t)q * 12 + ri) * C_ + f;
        const float* th = tl + 12 * C_;
        const float t0 = fmaf(fr, th[0 * C_] - tl[0 * C_], tl[0 * C_]);
        const float t1 = fmaf(fr, th[1 * C_] - tl[1 * C_], tl[1 * C_]);
        const float t2 = fmaf(fr, th[2 * C_] - tl[2 * C_], tl[2 * C_]);
        const float t3 = fmaf(fr, th[3 * C_] - tl[3 * C_], tl[3 * C_]);
        const float t4 = fmaf(fr, th[4 * C_] - tl[4 * C_], tl[4 * C_]);

        const float x0b = x0_in[b * C_ + f];
        const float xbx = x1_in[(b * 3 + 0) * C_ + f];
        const float xby = x1_in[(b * 3 + 1) * C_ + f];
        const float xbz = x1_in[(b * 3 + 2) * C_ + f];

        a0 = fmaf(t0, x0b, a0);
        const float tb = t1 * x0b;
        b1x = fmaf(tb, ux, b1x); b1y = fmaf(tb, uy, b1y); b1z = fmaf(tb, uz, b1z);
        a1x = fmaf(t2, xbx, a1x); a1y = fmaf(t2, xby, a1y); a1z = fmaf(t2, xbz, a1z);
        const float ud = fmaf(ux, xbx, fmaf(uy, xby, uz * xbz));
        o0 = fmaf(t3, ud, o0);
        const float crx = uy * xbz - uz * xby;
        const float cry = uz * xbx - ux * xbz;
        const float crz = ux * xby - uy * xbx;
        o1x = fmaf(t4, crx, o1x); o1y = fmaf(t4, cry, o1y); o1z = fmaf(t4, crz, o1z);
    }

    __shared__ float s[11][2][C_];
    s[0][half][f] = a0;
    s[1][half][f] = b1x; s[2][half][f] = b1y; s[3][half][f] = b1z;
    s[4][half][f] = a1x; s[5][half][f] = a1y; s[6][half][f] = a1z;
    s[7][half][f] = o0;
    s[8][half][f] = o1x; s[9][half][f] = o1y; s[10][half][f] = o1z;
    __syncthreads();

    // combine the two b-halves
    for (int idx = tid; idx < 11 * C_; idx += 256) {
        const int k = idx >> 7, c = idx & 127;
        s[k][0][c] += s[k][1][c];
    }
    __syncthreads();

    float y0 = 0.f, yx = 0.f, yy = 0.f, yz = 0.f;
    if (tid < 128) {
        y0 = b0v[f];
        const float* w0r = w0 + (size_t)f * (2 * C_);
        const float* w1r = w1 + (size_t)f * (3 * C_);
        for (int c = 0; c < C_; ++c) {
            y0 = fmaf(w0r[c],       s[0][0][c], y0);
            y0 = fmaf(w0r[C_ + c],  s[7][0][c], y0);
            const float wb = w1r[c], wa = w1r[C_ + c], wo = w1r[2 * C_ + c];
            yx = fmaf(wb, s[1][0][c], yx); yx = fmaf(wa, s[4][0][c], yx); yx = fmaf(wo, s[8][0][c],  yx);
            yy = fmaf(wb, s[2][0][c], yy); yy = fmaf(wa, s[5][0][c], yy); yy = fmaf(wo, s[9][0][c],  yy);
            yz = fmaf(wb, s[3][0][c], yz); yz = fmaf(wa, s[6][0][c], yz); yz = fmaf(wo, s[10][0][c], yz);
        }
    }

    if (NONLIN) {
        if (tid < 128) {
            const float x0v = y0 > 0.f ? y0 : expm1f(y0);
            const float nsq = fmaf(yx, yx, fmaf(yy, yy, yz * yz));
            const float nn  = sqrtf(fmaxf(nsq, 1e-12f));
            const float g   = nlb[f] + nn;
            const float sc  = (g > 0.f ? g : expm1f(g)) / nn;
            x0_out[a * C_ + f] = x0v;
            x1_out[(a * 3 + 0) * C_ + f] = yx * sc;
            x1_out[(a * 3 + 1) * C_ + f] = yy * sc;
            x1_out[(a * 3 + 2) * C_ + f] = yz * sc;
        }
    }
    if (LAST) {
        __syncthreads();   // all SI reads of s[] are done
        if (tid < 128) {
            out[a * C_ + f] = y0;                         // x0 output [N,C,1]
            float* o1 = out + N_ * C_;                    // x1 output [N,C,3]
            o1[a * (C_ * 3) + f * 3 + 0] = yx;
            o1[a * (C_ * 3) + f * 3 + 1] = yy;
            o1[a * (C_ * 3) + f * 3 + 2] = yz;
            s[0][0][f] = y0;                              // stage for atom head
        }
        __syncthreads();
        if (tid < 8) {
            float acc = predb[tid];
            for (int c = 0; c < C_; ++c)
                acc = fmaf(predW[tid * C_ + c], s[0][0][c], acc);
            out[N_ * C_ + N_ * C_ * 3 + a * 8 + tid] = acc;
        }
    }
}

// ---------------------------------------------------------------------------
extern "C" void kernel_launch(void* const* d_in, const int* in_sizes, int n_in,
                              void* d_out, int out_size, void* d_ws, size_t ws_size,
                              hipStream_t stream)
{
    const float* r       = (const float*)d_in[0];
    const float* onehot  = (const float*)d_in[1];
    const float* embed_W = (const float*)d_in[2];
    const float* embed_b = (const float*)d_in[3];
    const float* Rw1     = (const float*)d_in[4];
    const float* Rb1     = (const float*)d_in[5];
    const float* Rw2     = (const float*)d_in[6];
    const float* Rb2     = (const float*)d_in[7];
    const float* si0_w0  = (const float*)d_in[8];
    const float* si0_b0  = (const float*)d_in[9];
    const float* si0_w1  = (const float*)d_in[10];
    const float* si1_w0  = (const float*)d_in[11];
    const float* si1_b0  = (const float*)d_in[12];
    const float* si1_w1  = (const float*)d_in[13];
    const float* si2_w0  = (const float*)d_in[14];
    const float* si2_b0  = (const float*)d_in[15];
    const float* si2_w1  = (const float*)d_in[16];
    const float* nl_b0   = (const float*)d_in[17];
    const float* nl_b1   = (const float*)d_in[18];
    const float* pred_W  = (const float*)d_in[19];
    const float* pred_b  = (const float*)d_in[20];
    (void)in_sizes; (void)n_in; (void)out_size; (void)ws_size;

    float* ws    = (float*)d_ws;
    float* table = ws;                              // M_*12*C_
    float* e     = table + (size_t)M_ * 12 * C_;    // N_*C_
    float* x0a   = e   + N_ * C_;
    float* x1a   = x0a + N_ * C_;                   // N_*3*C_
    float* x0b   = x1a + N_ * 3 * C_;
    float* x1b   = x0b + N_ * C_;

    float* out = (float*)d_out;

    build_table_kernel<<<M_ / 8, 128, 0, stream>>>(Rw1, Rb1, Rw2, Rb2, table);
    embed_kernel<<<(N_ * C_) / 256, 256, 0, stream>>>(onehot, embed_W, embed_b, e);
    layer0_kernel<<<N_, 256, 0, stream>>>(r, e, table, si0_w0, si0_b0, si0_w1,
                                          nl_b0, x0a, x1a);
    full_layer_kernel<true, false><<<N_, 256, 0, stream>>>(
        r, x0a, x1a, table, 2, si1_w0, si1_b0, si1_w1, nl_b1,
        x0b, x1b, nullptr, nullptr, nullptr);
    full_layer_kernel<false, true><<<N_, 256, 0, stream>>>(
        r, x0b, x1b, table, 7, si2_w0, si2_b0, si2_w1, nullptr,
        nullptr, nullptr, out, pred_W, pred_b);
}

// Round 4
// 779.775 us; speedup vs baseline: 1.4028x; 1.4028x over previous
//
#include <hip/hip_runtime.h>
#include <math.h>

// ---------------------------------------------------------------------------
// TensorFieldNetwork on MI355X — round 2 design (3rd submit; rounds 2-3 never
// ran: GPU acquisition timeouts).
// rad_i(a,b) depends only on d_ab -> tabulate all 12 radial nets as
// {val, delta} float2 on an M-point grid; per-pair work = 5 lerped lookups.
// Layer kernels: 512 threads (f = tid&127, part = tid>>7, 4 b-partitions),
// per-pair geometry {u, t} precomputed ONCE per block into LDS (was computed
// redundantly by all 256 threads in round 1). SI tail parallelized 4-wide.
// ---------------------------------------------------------------------------

constexpr int   N_    = 768;
constexpr int   C_    = 128;
constexpr float DMAX_ = 32.0f;
constexpr float GAMMA_ = 1.6f;     // RBF / (HIGH - LOW)

// ---------------------------------------------------------------------------
// Kernel A: build radial tables, {val, delta} interleaved.
// grid = M/4 blocks x 256 threads; f = tid&127, fh = tid>>7 handles 6 filters.
// Each block covers m0..m0+3 (plus m0+4 value for the last delta).
// ---------------------------------------------------------------------------
__global__ __launch_bounds__(256) void build_table_kernel(
    const float* __restrict__ Rw1, const float* __restrict__ Rb1,
    const float* __restrict__ Rw2, const float* __restrict__ Rb2,
    float2* __restrict__ tab, int M, float delta)
{
    const int f  = threadIdx.x & 127, fh = threadIdx.x >> 7;
    const int m0 = blockIdx.x * 4;

    __shared__ float hs[2][5][C_];

    float rbf[5][4];
    const float cent[4] = {0.0f, 2.5f / 3.0f, 5.0f / 3.0f, 2.5f};
#pragma unroll
    for (int mm = 0; mm < 5; ++mm) {
        int m = m0 + mm; if (m > M - 1) m = M - 1;
        const float d = (float)m * delta;
#pragma unroll
        for (int k = 0; k < 4; ++k) {
            const float t = d - cent[k];
            rbf[mm][k] = expf(-GAMMA_ * t * t);
        }
    }

    for (int ii = 0; ii < 6; ++ii) {
        const int i = fh * 6 + ii;
        float w1v[4];
#pragma unroll
        for (int k = 0; k < 4; ++k) w1v[k] = Rw1[(i * 4 + k) * C_ + f];
        const float b1v = Rb1[i * C_ + f];

        __syncthreads();               // previous iteration's readers done
#pragma unroll
        for (int mm = 0; mm < 5; ++mm) {
            float acc = b1v;
#pragma unroll
            for (int k = 0; k < 4; ++k) acc = fmaf(rbf[mm][k], w1v[k], acc);
            hs[fh][mm][f] = fmaxf(acc, 0.0f);
        }
        __syncthreads();

        const float b2v = Rb2[i * C_ + f];
        float out[5] = {b2v, b2v, b2v, b2v, b2v};
        for (int c = 0; c < C_; ++c) {
            const float w = Rw2[(i * C_ + c) * C_ + f];
#pragma unroll
            for (int mm = 0; mm < 5; ++mm) out[mm] = fmaf(hs[fh][mm][c], w, out[mm]);
        }
#pragma unroll
        for (int mm = 0; mm < 4; ++mm) {
            const int m = m0 + mm;
            if (m < M)
                tab[((size_t)m * 12 + i) * C_ + f] =
                    make_float2(out[mm], out[mm + 1] - out[mm]);
        }
    }
}

// ---------------------------------------------------------------------------
// Kernel B: embedding  e[b,f] = one_hot[b,:] @ embed_W[f,:] + embed_b[f]
// ---------------------------------------------------------------------------
__global__ __launch_bounds__(256) void embed_kernel(
    const float* __restrict__ onehot, const float* __restrict__ eW,
    const float* __restrict__ eb, float* __restrict__ e)
{
    const int idx = blockIdx.x * 256 + threadIdx.x;
    const int b = idx >> 7, f = idx & 127;
    float acc = eb[f];
#pragma unroll
    for (int t = 0; t < 8; ++t) acc = fmaf(onehot[b * 8 + t], eW[f * 8 + t], acc);
    e[idx] = acc;
}

// ---------------------------------------------------------------------------
// Kernel C: layer 0. 512 threads: f = tid&127, part = tid>>7 (4 x 192 b's).
// ---------------------------------------------------------------------------
__global__ __launch_bounds__(512) void layer0_kernel(
    const float* __restrict__ r, const float* __restrict__ e,
    const float2* __restrict__ tab, int M, float inv_delta,
    const float* __restrict__ w0, const float* __restrict__ b0v,
    const float* __restrict__ w1, const float* __restrict__ nlb,
    float* __restrict__ x0_out, float* __restrict__ x1_out)
{
    const int a = blockIdx.x, tid = threadIdx.x;

    __shared__ float  smem[2304];   // r staging (2304), then sred[4][4][128]
    __shared__ float4 pair[N_];     // {ux, uy, uz, t = d*inv_delta}
    __shared__ float  ys[4 * C_];

    for (int i = tid; i < N_ * 3; i += 512) smem[i] = r[i];
    __syncthreads();
    {
        const float rax = smem[a * 3 + 0], ray = smem[a * 3 + 1], raz = smem[a * 3 + 2];
        for (int b = tid; b < N_; b += 512) {
            const float dx = rax - smem[b * 3 + 0];
            const float dy = ray - smem[b * 3 + 1];
            const float dz = raz - smem[b * 3 + 2];
            const float d2 = fmaf(dx, dx, fmaf(dy, dy, dz * dz));
            const float d  = sqrtf(fmaxf(d2, 1e-12f));
            const float inv = 1.0f / (d + 1e-8f);
            pair[b] = make_float4(dx * inv, dy * inv, dz * inv, d * inv_delta);
        }
    }
    __syncthreads();

    const int f = tid & 127, part = tid >> 7;
    float c00 = 0.f, cx = 0.f, cy = 0.f, cz = 0.f;
    const int bEnd = part * 192 + 192;
#pragma unroll 2
    for (int b = part * 192; b < bEnd; ++b) {
        const float4 p = pair[b];
        int q = (int)p.w; q = q > M - 2 ? M - 2 : q;
        const float fr = p.w - (float)q;
        const float2* tp = tab + ((size_t)q * 12) * C_ + f;
        const float2 v0 = tp[0];
        const float2 v1 = tp[C_];
        const float t0 = fmaf(fr, v0.y, v0.x);
        const float t1 = fmaf(fr, v1.y, v1.x);
        const float eb_ = e[b * C_ + f];
        c00 = fmaf(t0, eb_, c00);
        const float te = t1 * eb_;
        cx = fmaf(te, p.x, cx); cy = fmaf(te, p.y, cy); cz = fmaf(te, p.z, cz);
    }

    // sred[k][part][f] at smem[(k*4+part)*C_ + f]
    smem[(0 * 4 + part) * C_ + f] = c00;
    smem[(1 * 4 + part) * C_ + f] = cx;
    smem[(2 * 4 + part) * C_ + f] = cy;
    smem[(3 * 4 + part) * C_ + f] = cz;
    __syncthreads();
    {   // reduce 4 parts -> compact s[k][c] at smem[k*C_ + c]
        const int k = tid >> 7, c = tid & 127;
        const float s = smem[(k * 4 + 0) * C_ + c] + smem[(k * 4 + 1) * C_ + c]
                      + smem[(k * 4 + 2) * C_ + c] + smem[(k * 4 + 3) * C_ + c];
        __syncthreads();
        smem[k * C_ + c] = s;
    }
    __syncthreads();

    {   // self-interaction: group j = tid>>7 computes output component j
        const int j = tid >> 7;
        float y;
        if (j == 0) {
            y = b0v[f];
            const float4* w = (const float4*)(w0 + (size_t)f * C_);
            for (int c4 = 0; c4 < C_ / 4; ++c4) {
                const float4 wv = w[c4];
                y = fmaf(wv.x, smem[c4 * 4 + 0], y);
                y = fmaf(wv.y, smem[c4 * 4 + 1], y);
                y = fmaf(wv.z, smem[c4 * 4 + 2], y);
                y = fmaf(wv.w, smem[c4 * 4 + 3], y);
            }
        } else {
            y = 0.f;
            const float4* w = (const float4*)(w1 + (size_t)f * C_);
            const float* sj = smem + j * C_;
            for (int c4 = 0; c4 < C_ / 4; ++c4) {
                const float4 wv = w[c4];
                y = fmaf(wv.x, sj[c4 * 4 + 0], y);
                y = fmaf(wv.y, sj[c4 * 4 + 1], y);
                y = fmaf(wv.z, sj[c4 * 4 + 2], y);
                y = fmaf(wv.w, sj[c4 * 4 + 3], y);
            }
        }
        ys[j * C_ + f] = y;
    }
    __syncthreads();

    if (tid < C_) {
        const float y0 = ys[tid];
        const float yx = ys[C_ + tid], yy = ys[2 * C_ + tid], yz = ys[3 * C_ + tid];
        const float x0v = y0 > 0.f ? y0 : expm1f(y0);
        const float nsq = fmaf(yx, yx, fmaf(yy, yy, yz * yz));
        const float nn  = sqrtf(fmaxf(nsq, 1e-12f));
        const float g   = nlb[tid] + nn;
        const float sc  = (g > 0.f ? g : expm1f(g)) / nn;
        x0_out[a * C_ + tid] = x0v;
        x1_out[(a * 3 + 0) * C_ + tid] = yx * sc;
        x1_out[(a * 3 + 1) * C_ + tid] = yy * sc;
        x1_out[(a * 3 + 2) * C_ + tid] = yz * sc;
    }
}

// ---------------------------------------------------------------------------
// Kernel D: full layer. 512 threads, 4 b-partitions, 11 accumulators.
// ---------------------------------------------------------------------------
template <bool NONLIN, bool LAST, int RI>
__global__ __launch_bounds__(512) void full_layer_kernel(
    const float* __restrict__ r,
    const float* __restrict__ x0_in, const float* __restrict__ x1_in,
    const float2* __restrict__ tab, int M, float inv_delta,
    const float* __restrict__ w0, const float* __restrict__ b0v,
    const float* __restrict__ w1, const float* __restrict__ nlb,
    float* __restrict__ x0_out, float* __restrict__ x1_out,
    float* __restrict__ out, const float* __restrict__ predW,
    const float* __restrict__ predb)
{
    const int a = blockIdx.x, tid = threadIdx.x;

    __shared__ float  smem[11 * 4 * C_];   // 5632: r staging, sred, compact s
    __shared__ float4 pair[N_];
    __shared__ float  ys[4 * C_];

    for (int i = tid; i < N_ * 3; i += 512) smem[i] = r[i];
    __syncthreads();
    {
        const float rax = smem[a * 3 + 0], ray = smem[a * 3 + 1], raz = smem[a * 3 + 2];
        for (int b = tid; b < N_; b += 512) {
            const float dx = rax - smem[b * 3 + 0];
            const float dy = ray - smem[b * 3 + 1];
            const float dz = raz - smem[b * 3 + 2];
            const float d2 = fmaf(dx, dx, fmaf(dy, dy, dz * dz));
            const float d  = sqrtf(fmaxf(d2, 1e-12f));
            const float inv = 1.0f / (d + 1e-8f);
            pair[b] = make_float4(dx * inv, dy * inv, dz * inv, d * inv_delta);
        }
    }
    __syncthreads();

    const int f = tid & 127, part = tid >> 7;
    float a0 = 0.f, b1x = 0.f, b1y = 0.f, b1z = 0.f;
    float a1x = 0.f, a1y = 0.f, a1z = 0.f;
    float o0 = 0.f, o1x = 0.f, o1y = 0.f, o1z = 0.f;

    const int bEnd = part * 192 + 192;
#pragma unroll 2
    for (int b = part * 192; b < bEnd; ++b) {
        const float4 p = pair[b];
        int q = (int)p.w; q = q > M - 2 ? M - 2 : q;
        const float fr = p.w - (float)q;
        const float2* tp = tab + ((size_t)q * 12 + RI) * C_ + f;
        const float2 v0 = tp[0 * C_];
        const float2 v1 = tp[1 * C_];
        const float2 v2 = tp[2 * C_];
        const float2 v3 = tp[3 * C_];
        const float2 v4 = tp[4 * C_];
        const float t0 = fmaf(fr, v0.y, v0.x);
        const float t1 = fmaf(fr, v1.y, v1.x);
        const float t2 = fmaf(fr, v2.y, v2.x);
        const float t3 = fmaf(fr, v3.y, v3.x);
        const float t4 = fmaf(fr, v4.y, v4.x);

        const float x0b = x0_in[b * C_ + f];
        const float xbx = x1_in[(b * 3 + 0) * C_ + f];
        const float xby = x1_in[(b * 3 + 1) * C_ + f];
        const float xbz = x1_in[(b * 3 + 2) * C_ + f];

        a0 = fmaf(t0, x0b, a0);
        const float tb = t1 * x0b;
        b1x = fmaf(tb, p.x, b1x); b1y = fmaf(tb, p.y, b1y); b1z = fmaf(tb, p.z, b1z);
        a1x = fmaf(t2, xbx, a1x); a1y = fmaf(t2, xby, a1y); a1z = fmaf(t2, xbz, a1z);
        const float ud = fmaf(p.x, xbx, fmaf(p.y, xby, p.z * xbz));
        o0 = fmaf(t3, ud, o0);
        const float crx = p.y * xbz - p.z * xby;
        const float cry = p.z * xbx - p.x * xbz;
        const float crz = p.x * xby - p.y * xbx;
        o1x = fmaf(t4, crx, o1x); o1y = fmaf(t4, cry, o1y); o1z = fmaf(t4, crz, o1z);
    }

    // sred[k][part][f]
    smem[(0 * 4 + part) * C_ + f] = a0;
    smem[(1 * 4 + part) * C_ + f] = b1x;
    smem[(2 * 4 + part) * C_ + f] = b1y;
    smem[(3 * 4 + part) * C_ + f] = b1z;
    smem[(4 * 4 + part) * C_ + f] = a1x;
    smem[(5 * 4 + part) * C_ + f] = a1y;
    smem[(6 * 4 + part) * C_ + f] = a1z;
    smem[(7 * 4 + part) * C_ + f] = o0;
    smem[(8 * 4 + part) * C_ + f] = o1x;
    smem[(9 * 4 + part) * C_ + f] = o1y;
    smem[(10 * 4 + part) * C_ + f] = o1z;
    __syncthreads();

    {   // reduce 11*128 = 1408 elements -> compact s[k][c] = smem[k*C_+c]
        const int i0 = tid, i1 = tid + 512, i2 = tid + 1024;
        const bool has2 = i2 < 11 * C_;
        float r0, r1, r2 = 0.f;
        {
            const int k = i0 >> 7, c = i0 & 127;
            r0 = smem[(k * 4 + 0) * C_ + c] + smem[(k * 4 + 1) * C_ + c]
               + smem[(k * 4 + 2) * C_ + c] + smem[(k * 4 + 3) * C_ + c];
        }
        {
            const int k = i1 >> 7, c = i1 & 127;
            r1 = smem[(k * 4 + 0) * C_ + c] + smem[(k * 4 + 1) * C_ + c]
               + smem[(k * 4 + 2) * C_ + c] + smem[(k * 4 + 3) * C_ + c];
        }
        if (has2) {
            const int k = i2 >> 7, c = i2 & 127;
            r2 = smem[(k * 4 + 0) * C_ + c] + smem[(k * 4 + 1) * C_ + c]
               + smem[(k * 4 + 2) * C_ + c] + smem[(k * 4 + 3) * C_ + c];
        }
        __syncthreads();
        smem[i0] = r0;
        smem[i1] = r1;
        if (has2) smem[i2] = r2;
    }
    __syncthreads();

    {   // SI: j = tid>>7; j=0 -> y0 (w0, s0/s7), j=1..3 -> y_j (w1, s_j/s_{3+j}/s_{7+j})
        const int j = tid >> 7;
        float y;
        if (j == 0) {
            y = b0v[f];
            const float4* w = (const float4*)(w0 + (size_t)f * (2 * C_));
            const float* s0 = smem + 0 * C_;
            const float* s7 = smem + 7 * C_;
            for (int c4 = 0; c4 < C_ / 4; ++c4) {
                const float4 wa = w[c4];
                const float4 wb = w[C_ / 4 + c4];
                y = fmaf(wa.x, s0[c4 * 4 + 0], y);
                y = fmaf(wa.y, s0[c4 * 4 + 1], y);
                y = fmaf(wa.z, s0[c4 * 4 + 2], y);
                y = fmaf(wa.w, s0[c4 * 4 + 3], y);
                y = fmaf(wb.x, s7[c4 * 4 + 0], y);
                y = fmaf(wb.y, s7[c4 * 4 + 1], y);
                y = fmaf(wb.z, s7[c4 * 4 + 2], y);
                y = fmaf(wb.w, s7[c4 * 4 + 3], y);
            }
        } else {
            y = 0.f;
            const float4* w = (const float4*)(w1 + (size_t)f * (3 * C_));
            const float* sb = smem + j * C_;
            const float* sa = smem + (3 + j) * C_;
            const float* so = smem + (7 + j) * C_;
            for (int c4 = 0; c4 < C_ / 4; ++c4) {
                const float4 w_b = w[c4];
                const float4 w_a = w[C_ / 4 + c4];
                const float4 w_o = w[2 * (C_ / 4) + c4];
                y = fmaf(w_b.x, sb[c4 * 4 + 0], y);
                y = fmaf(w_b.y, sb[c4 * 4 + 1], y);
                y = fmaf(w_b.z, sb[c4 * 4 + 2], y);
                y = fmaf(w_b.w, sb[c4 * 4 + 3], y);
                y = fmaf(w_a.x, sa[c4 * 4 + 0], y);
                y = fmaf(w_a.y, sa[c4 * 4 + 1], y);
                y = fmaf(w_a.z, sa[c4 * 4 + 2], y);
                y = fmaf(w_a.w, sa[c4 * 4 + 3], y);
                y = fmaf(w_o.x, so[c4 * 4 + 0], y);
                y = fmaf(w_o.y, so[c4 * 4 + 1], y);
                y = fmaf(w_o.z, so[c4 * 4 + 2], y);
                y = fmaf(w_o.w, so[c4 * 4 + 3], y);
            }
        }
        ys[j * C_ + f] = y;
    }
    __syncthreads();

    if (NONLIN) {
        if (tid < C_) {
            const float y0 = ys[tid];
            const float yx = ys[C_ + tid], yy = ys[2 * C_ + tid], yz = ys[3 * C_ + tid];
            const float x0v = y0 > 0.f ? y0 : expm1f(y0);
            const float nsq = fmaf(yx, yx, fmaf(yy, yy, yz * yz));
            const float nn  = sqrtf(fmaxf(nsq, 1e-12f));
            const float g   = nlb[tid] + nn;
            const float sc  = (g > 0.f ? g : expm1f(g)) / nn;
            x0_out[a * C_ + tid] = x0v;
            x1_out[(a * 3 + 0) * C_ + tid] = yx * sc;
            x1_out[(a * 3 + 1) * C_ + tid] = yy * sc;
            x1_out[(a * 3 + 2) * C_ + tid] = yz * sc;
        }
    }
    if (LAST) {
        if (tid < C_) {
            const float y0 = ys[tid];
            const float yx = ys[C_ + tid], yy = ys[2 * C_ + tid], yz = ys[3 * C_ + tid];
            out[a * C_ + tid] = y0;                   // x0 [N,C,1]
            float* o1 = out + N_ * C_;                // x1 [N,C,3]
            o1[a * (C_ * 3) + tid * 3 + 0] = yx;
            o1[a * (C_ * 3) + tid * 3 + 1] = yy;
            o1[a * (C_ * 3) + tid * 3 + 2] = yz;
        }
        __syncthreads();
        if (tid < 8) {                                // atom head from ys[0..127]
            float acc = predb[tid];
            for (int c = 0; c < C_; ++c)
                acc = fmaf(predW[tid * C_ + c], ys[c], acc);
            out[N_ * C_ + N_ * C_ * 3 + a * 8 + tid] = acc;
        }
    }
}

// ---------------------------------------------------------------------------
extern "C" void kernel_launch(void* const* d_in, const int* in_sizes, int n_in,
                              void* d_out, int out_size, void* d_ws, size_t ws_size,
                              hipStream_t stream)
{
    const float* r       = (const float*)d_in[0];
    const float* onehot  = (const float*)d_in[1];
    const float* embed_W = (const float*)d_in[2];
    const float* embed_b = (const float*)d_in[3];
    const float* Rw1     = (const float*)d_in[4];
    const float* Rb1     = (const float*)d_in[5];
    const float* Rw2     = (const float*)d_in[6];
    const float* Rb2     = (const float*)d_in[7];
    const float* si0_w0  = (const float*)d_in[8];
    const float* si0_b0  = (const float*)d_in[9];
    const float* si0_w1  = (const float*)d_in[10];
    const float* si1_w0  = (const float*)d_in[11];
    const float* si1_b0  = (const float*)d_in[12];
    const float* si1_w1  = (const float*)d_in[13];
    const float* si2_w0  = (const float*)d_in[14];
    const float* si2_b0  = (const float*)d_in[15];
    const float* si2_w1  = (const float*)d_in[16];
    const float* nl_b0   = (const float*)d_in[17];
    const float* nl_b1   = (const float*)d_in[18];
    const float* pred_W  = (const float*)d_in[19];
    const float* pred_b  = (const float*)d_in[20];
    (void)in_sizes; (void)n_in; (void)out_size;

    // choose table resolution by available workspace (M=1024 path needs
    // exactly what round 1 proved fits)
    const size_t bufs_f = (size_t)N_ * C_ * 3 + (size_t)N_ * 3 * C_ * 2; // e,x0a,x0b,x1a,x1b
    int M = 2048;
    if ((((size_t)M * 12 * C_ * 2 + bufs_f) * 4) > ws_size) M = 1024;
    const float delta     = DMAX_ / (float)(M - 1);
    const float inv_delta = (float)(M - 1) / DMAX_;

    float*  ws    = (float*)d_ws;
    float2* table = (float2*)ws;                         // M*12*C_ float2
    float*  e     = ws + (size_t)M * 12 * C_ * 2;
    float*  x0a   = e   + N_ * C_;
    float*  x1a   = x0a + N_ * C_;                       // [N][3][C]
    float*  x0b   = x1a + N_ * 3 * C_;
    float*  x1b   = x0b + N_ * C_;

    float* out = (float*)d_out;

    build_table_kernel<<<M / 4, 256, 0, stream>>>(Rw1, Rb1, Rw2, Rb2, table, M, delta);
    embed_kernel<<<(N_ * C_) / 256, 256, 0, stream>>>(onehot, embed_W, embed_b, e);
    layer0_kernel<<<N_, 512, 0, stream>>>(r, e, table, M, inv_delta,
                                          si0_w0, si0_b0, si0_w1, nl_b0, x0a, x1a);
    full_layer_kernel<true, false, 2><<<N_, 512, 0, stream>>>(
        r, x0a, x1a, table, M, inv_delta, si1_w0, si1_b0, si1_w1, nl_b1,
        x0b, x1b, nullptr, nullptr, nullptr);
    full_layer_kernel<false, true, 7><<<N_, 512, 0, stream>>>(
        r, x0b, x1b, table, M, inv_delta, si2_w0, si2_b0, si2_w1, nullptr,
        nullptr, nullptr, out, pred_W, pred_b);
}

// Round 5
// 517.916 us; speedup vs baseline: 2.1120x; 1.5056x over previous
//
#include <hip/hip_runtime.h>
#include <hip/hip_fp16.h>
#include <math.h>

// ---------------------------------------------------------------------------
// TensorFieldNetwork on MI355X — round 5.
// Round-4 PMC: full_layer 304us, VALUBusy 39%, occ 60%, HBM 2.4% ->
// latency/L3-BW bound on 25MB table reads (9.7 TB/s of L2/L3 traffic).
// Fixes: (a) DMAX 32->6.4 with exact asymptotic clamp (rbf ~ e^-24 at 6.4),
// M=512 -> finer grid than before; (b) table entries fp16 {val,delta} ->
// 3.1MB, fits every XCD's 4MB L2; (c) x0/x1 packed [N][4][C] single-base;
// (d) 2x-unrolled pair loop for load ILP.
// ---------------------------------------------------------------------------

constexpr int   N_    = 768;
constexpr int   C_    = 128;
constexpr int   M_    = 512;
constexpr float DMAX_ = 6.4f;
constexpr float GAMMA_ = 1.6f;     // RBF / (HIGH - LOW)

// ---------------------------------------------------------------------------
// Kernel A: build radial tables, fp16 {val, delta} packed in __half2.
// grid = M/4 blocks x 256 threads; f = tid&127, fh = tid>>7 handles 6 filters.
// ---------------------------------------------------------------------------
__global__ __launch_bounds__(256) void build_table_kernel(
    const float* __restrict__ Rw1, const float* __restrict__ Rb1,
    const float* __restrict__ Rw2, const float* __restrict__ Rb2,
    __half2* __restrict__ tab, float delta)
{
    const int f  = threadIdx.x & 127, fh = threadIdx.x >> 7;
    const int m0 = blockIdx.x * 4;

    __shared__ float hs[2][5][C_];

    float rbf[5][4];
    const float cent[4] = {0.0f, 2.5f / 3.0f, 5.0f / 3.0f, 2.5f};
#pragma unroll
    for (int mm = 0; mm < 5; ++mm) {
        int m = m0 + mm; if (m > M_ - 1) m = M_ - 1;
        const float d = (float)m * delta;
#pragma unroll
        for (int k = 0; k < 4; ++k) {
            const float t = d - cent[k];
            rbf[mm][k] = expf(-GAMMA_ * t * t);
        }
    }

    for (int ii = 0; ii < 6; ++ii) {
        const int i = fh * 6 + ii;
        float w1v[4];
#pragma unroll
        for (int k = 0; k < 4; ++k) w1v[k] = Rw1[(i * 4 + k) * C_ + f];
        const float b1v = Rb1[i * C_ + f];

        __syncthreads();               // previous iteration's readers done
#pragma unroll
        for (int mm = 0; mm < 5; ++mm) {
            float acc = b1v;
#pragma unroll
            for (int k = 0; k < 4; ++k) acc = fmaf(rbf[mm][k], w1v[k], acc);
            hs[fh][mm][f] = fmaxf(acc, 0.0f);
        }
        __syncthreads();

        const float b2v = Rb2[i * C_ + f];
        float out[5] = {b2v, b2v, b2v, b2v, b2v};
        for (int c = 0; c < C_; ++c) {
            const float w = Rw2[(i * C_ + c) * C_ + f];
#pragma unroll
            for (int mm = 0; mm < 5; ++mm) out[mm] = fmaf(hs[fh][mm][c], w, out[mm]);
        }
#pragma unroll
        for (int mm = 0; mm < 4; ++mm) {
            const int m = m0 + mm;
            if (m < M_)
                tab[((size_t)m * 12 + i) * C_ + f] =
                    __floats2half2_rn(out[mm], out[mm + 1] - out[mm]);
        }
    }
}

// ---------------------------------------------------------------------------
// Kernel B: embedding  e[b,f] = one_hot[b,:] @ embed_W[f,:] + embed_b[f]
// ---------------------------------------------------------------------------
__global__ __launch_bounds__(256) void embed_kernel(
    const float* __restrict__ onehot, const float* __restrict__ eW,
    const float* __restrict__ eb, float* __restrict__ e)
{
    const int idx = blockIdx.x * 256 + threadIdx.x;
    const int b = idx >> 7, f = idx & 127;
    float acc = eb[f];
#pragma unroll
    for (int t = 0; t < 8; ++t) acc = fmaf(onehot[b * 8 + t], eW[f * 8 + t], acc);
    e[idx] = acc;
}

// ---------------------------------------------------------------------------
// Kernel C: layer 0. 512 threads: f = tid&127, part = tid>>7 (4 x 192 b's).
// x output packed [N][4][C]: row0 = x0, rows 1-3 = x1 xyz.
// ---------------------------------------------------------------------------
__global__ __launch_bounds__(512) void layer0_kernel(
    const float* __restrict__ r, const float* __restrict__ e,
    const __half2* __restrict__ tab, float inv_delta,
    const float* __restrict__ w0, const float* __restrict__ b0v,
    const float* __restrict__ w1, const float* __restrict__ nlb,
    float* __restrict__ xout)
{
    const int a = blockIdx.x, tid = threadIdx.x;

    __shared__ float  smem[2304];   // r staging (2304), then sred[4][4][128]
    __shared__ float4 pair[N_];     // {ux, uy, uz, t = d*inv_delta}
    __shared__ float  ys[4 * C_];

    for (int i = tid; i < N_ * 3; i += 512) smem[i] = r[i];
    __syncthreads();
    {
        const float rax = smem[a * 3 + 0], ray = smem[a * 3 + 1], raz = smem[a * 3 + 2];
        for (int b = tid; b < N_; b += 512) {
            const float dx = rax - smem[b * 3 + 0];
            const float dy = ray - smem[b * 3 + 1];
            const float dz = raz - smem[b * 3 + 2];
            const float d2 = fmaf(dx, dx, fmaf(dy, dy, dz * dz));
            const float d  = sqrtf(fmaxf(d2, 1e-12f));
            const float inv = 1.0f / (d + 1e-8f);
            pair[b] = make_float4(dx * inv, dy * inv, dz * inv, d * inv_delta);
        }
    }
    __syncthreads();

    const int f = tid & 127, part = tid >> 7;
    float c00 = 0.f, cx = 0.f, cy = 0.f, cz = 0.f;
    const int bBeg = part * 192, bEnd = bBeg + 192;
#pragma unroll 2
    for (int b = bBeg; b < bEnd; b += 2) {
        const float4 pA = pair[b];
        const float4 pB = pair[b + 1];
        int qA = (int)pA.w; qA = qA > M_ - 2 ? M_ - 2 : qA;
        int qB = (int)pB.w; qB = qB > M_ - 2 ? M_ - 2 : qB;
        const float frA = fminf(pA.w - (float)qA, 1.0f);
        const float frB = fminf(pB.w - (float)qB, 1.0f);
        const __half2* tpA = tab + ((size_t)qA * 12) * C_ + f;
        const __half2* tpB = tab + ((size_t)qB * 12) * C_ + f;
        const __half2 hA0 = tpA[0 * C_], hA1 = tpA[1 * C_];
        const __half2 hB0 = tpB[0 * C_], hB1 = tpB[1 * C_];
        const float eA = e[b * C_ + f];
        const float eB = e[(b + 1) * C_ + f];

        {
            const float2 v0 = __half22float2(hA0);
            const float2 v1 = __half22float2(hA1);
            const float t0 = fmaf(frA, v0.y, v0.x);
            const float t1 = fmaf(frA, v1.y, v1.x);
            c00 = fmaf(t0, eA, c00);
            const float te = t1 * eA;
            cx = fmaf(te, pA.x, cx); cy = fmaf(te, pA.y, cy); cz = fmaf(te, pA.z, cz);
        }
        {
            const float2 v0 = __half22float2(hB0);
            const float2 v1 = __half22float2(hB1);
            const float t0 = fmaf(frB, v0.y, v0.x);
            const float t1 = fmaf(frB, v1.y, v1.x);
            c00 = fmaf(t0, eB, c00);
            const float te = t1 * eB;
            cx = fmaf(te, pB.x, cx); cy = fmaf(te, pB.y, cy); cz = fmaf(te, pB.z, cz);
        }
    }

    // sred[k][part][f] at smem[(k*4+part)*C_ + f]
    smem[(0 * 4 + part) * C_ + f] = c00;
    smem[(1 * 4 + part) * C_ + f] = cx;
    smem[(2 * 4 + part) * C_ + f] = cy;
    smem[(3 * 4 + part) * C_ + f] = cz;
    __syncthreads();
    {   // reduce 4 parts -> compact s[k][c] at smem[k*C_ + c]
        const int k = tid >> 7, c = tid & 127;
        const float s = smem[(k * 4 + 0) * C_ + c] + smem[(k * 4 + 1) * C_ + c]
                      + smem[(k * 4 + 2) * C_ + c] + smem[(k * 4 + 3) * C_ + c];
        __syncthreads();
        smem[k * C_ + c] = s;
    }
    __syncthreads();

    {   // self-interaction: group j = tid>>7 computes output component j
        const int j = tid >> 7;
        float y;
        if (j == 0) {
            y = b0v[f];
            const float4* w = (const float4*)(w0 + (size_t)f * C_);
            for (int c4 = 0; c4 < C_ / 4; ++c4) {
                const float4 wv = w[c4];
                y = fmaf(wv.x, smem[c4 * 4 + 0], y);
                y = fmaf(wv.y, smem[c4 * 4 + 1], y);
                y = fmaf(wv.z, smem[c4 * 4 + 2], y);
                y = fmaf(wv.w, smem[c4 * 4 + 3], y);
            }
        } else {
            y = 0.f;
            const float4* w = (const float4*)(w1 + (size_t)f * C_);
            const float* sj = smem + j * C_;
            for (int c4 = 0; c4 < C_ / 4; ++c4) {
                const float4 wv = w[c4];
                y = fmaf(wv.x, sj[c4 * 4 + 0], y);
                y = fmaf(wv.y, sj[c4 * 4 + 1], y);
                y = fmaf(wv.z, sj[c4 * 4 + 2], y);
                y = fmaf(wv.w, sj[c4 * 4 + 3], y);
            }
        }
        ys[j * C_ + f] = y;
    }
    __syncthreads();

    if (tid < C_) {
        const float y0 = ys[tid];
        const float yx = ys[C_ + tid], yy = ys[2 * C_ + tid], yz = ys[3 * C_ + tid];
        const float x0v = y0 > 0.f ? y0 : expm1f(y0);
        const float nsq = fmaf(yx, yx, fmaf(yy, yy, yz * yz));
        const float nn  = sqrtf(fmaxf(nsq, 1e-12f));
        const float g   = nlb[tid] + nn;
        const float sc  = (g > 0.f ? g : expm1f(g)) / nn;
        float* xo = xout + (size_t)a * 4 * C_ + tid;
        xo[0 * C_] = x0v;
        xo[1 * C_] = yx * sc;
        xo[2 * C_] = yy * sc;
        xo[3 * C_] = yz * sc;
    }
}

// ---------------------------------------------------------------------------
// Kernel D: full layer. 512 threads, 4 b-partitions, 11 accumulators.
// x input/output packed [N][4][C] (row0 = x0, rows 1-3 = x1 xyz).
// ---------------------------------------------------------------------------
template <bool NONLIN, bool LAST, int RI>
__global__ __launch_bounds__(512) void full_layer_kernel(
    const float* __restrict__ r,
    const float* __restrict__ xin,
    const __half2* __restrict__ tab, float inv_delta,
    const float* __restrict__ w0, const float* __restrict__ b0v,
    const float* __restrict__ w1, const float* __restrict__ nlb,
    float* __restrict__ xout,
    float* __restrict__ out, const float* __restrict__ predW,
    const float* __restrict__ predb)
{
    const int a = blockIdx.x, tid = threadIdx.x;

    __shared__ float  smem[11 * 4 * C_];   // 5632: r staging, sred, compact s
    __shared__ float4 pair[N_];
    __shared__ float  ys[4 * C_];

    for (int i = tid; i < N_ * 3; i += 512) smem[i] = r[i];
    __syncthreads();
    {
        const float rax = smem[a * 3 + 0], ray = smem[a * 3 + 1], raz = smem[a * 3 + 2];
        for (int b = tid; b < N_; b += 512) {
            const float dx = rax - smem[b * 3 + 0];
            const float dy = ray - smem[b * 3 + 1];
            const float dz = raz - smem[b * 3 + 2];
            const float d2 = fmaf(dx, dx, fmaf(dy, dy, dz * dz));
            const float d  = sqrtf(fmaxf(d2, 1e-12f));
            const float inv = 1.0f / (d + 1e-8f);
            pair[b] = make_float4(dx * inv, dy * inv, dz * inv, d * inv_delta);
        }
    }
    __syncthreads();

    const int f = tid & 127, part = tid >> 7;
    float a0 = 0.f, b1x = 0.f, b1y = 0.f, b1z = 0.f;
    float a1x = 0.f, a1y = 0.f, a1z = 0.f;
    float o0 = 0.f, o1x = 0.f, o1y = 0.f, o1z = 0.f;

    const int bBeg = part * 192, bEnd = bBeg + 192;
#pragma unroll 2
    for (int b = bBeg; b < bEnd; b += 2) {
        const float4 pA = pair[b];
        const float4 pB = pair[b + 1];
        int qA = (int)pA.w; qA = qA > M_ - 2 ? M_ - 2 : qA;
        int qB = (int)pB.w; qB = qB > M_ - 2 ? M_ - 2 : qB;
        const float frA = fminf(pA.w - (float)qA, 1.0f);
        const float frB = fminf(pB.w - (float)qB, 1.0f);
        const __half2* tpA = tab + ((size_t)qA * 12 + RI) * C_ + f;
        const __half2* tpB = tab + ((size_t)qB * 12 + RI) * C_ + f;
        const __half2 hA0 = tpA[0 * C_], hA1 = tpA[1 * C_], hA2 = tpA[2 * C_];
        const __half2 hA3 = tpA[3 * C_], hA4 = tpA[4 * C_];
        const __half2 hB0 = tpB[0 * C_], hB1 = tpB[1 * C_], hB2 = tpB[2 * C_];
        const __half2 hB3 = tpB[3 * C_], hB4 = tpB[4 * C_];
        const float* xA = xin + (size_t)b * 4 * C_ + f;
        const float* xB = xA + 4 * C_;
        const float xA0 = xA[0 * C_], xAx = xA[1 * C_], xAy = xA[2 * C_], xAz = xA[3 * C_];
        const float xB0 = xB[0 * C_], xBx = xB[1 * C_], xBy = xB[2 * C_], xBz = xB[3 * C_];

        {
            const float2 v0 = __half22float2(hA0);
            const float2 v1 = __half22float2(hA1);
            const float2 v2 = __half22float2(hA2);
            const float2 v3 = __half22float2(hA3);
            const float2 v4 = __half22float2(hA4);
            const float t0 = fmaf(frA, v0.y, v0.x);
            const float t1 = fmaf(frA, v1.y, v1.x);
            const float t2 = fmaf(frA, v2.y, v2.x);
            const float t3 = fmaf(frA, v3.y, v3.x);
            const float t4 = fmaf(frA, v4.y, v4.x);
            a0 = fmaf(t0, xA0, a0);
            const float tb = t1 * xA0;
            b1x = fmaf(tb, pA.x, b1x); b1y = fmaf(tb, pA.y, b1y); b1z = fmaf(tb, pA.z, b1z);
            a1x = fmaf(t2, xAx, a1x); a1y = fmaf(t2, xAy, a1y); a1z = fmaf(t2, xAz, a1z);
            const float ud = fmaf(pA.x, xAx, fmaf(pA.y, xAy, pA.z * xAz));
            o0 = fmaf(t3, ud, o0);
            const float crx = pA.y * xAz - pA.z * xAy;
            const float cry = pA.z * xAx - pA.x * xAz;
            const float crz = pA.x * xAy - pA.y * xAx;
            o1x = fmaf(t4, crx, o1x); o1y = fmaf(t4, cry, o1y); o1z = fmaf(t4, crz, o1z);
        }
        {
            const float2 v0 = __half22float2(hB0);
            const float2 v1 = __half22float2(hB1);
            const float2 v2 = __half22float2(hB2);
            const float2 v3 = __half22float2(hB3);
            const float2 v4 = __half22float2(hB4);
            const float t0 = fmaf(frB, v0.y, v0.x);
            const float t1 = fmaf(frB, v1.y, v1.x);
            const float t2 = fmaf(frB, v2.y, v2.x);
            const float t3 = fmaf(frB, v3.y, v3.x);
            const float t4 = fmaf(frB, v4.y, v4.x);
            a0 = fmaf(t0, xB0, a0);
            const float tb = t1 * xB0;
            b1x = fmaf(tb, pB.x, b1x); b1y = fmaf(tb, pB.y, b1y); b1z = fmaf(tb, pB.z, b1z);
            a1x = fmaf(t2, xBx, a1x); a1y = fmaf(t2, xBy, a1y); a1z = fmaf(t2, xBz, a1z);
            const float ud = fmaf(pB.x, xBx, fmaf(pB.y, xBy, pB.z * xBz));
            o0 = fmaf(t3, ud, o0);
            const float crx = pB.y * xBz - pB.z * xBy;
            const float cry = pB.z * xBx - pB.x * xBz;
            const float crz = pB.x * xBy - pB.y * xBx;
            o1x = fmaf(t4, crx, o1x); o1y = fmaf(t4, cry, o1y); o1z = fmaf(t4, crz, o1z);
        }
    }

    // sred[k][part][f]
    smem[(0 * 4 + part) * C_ + f] = a0;
    smem[(1 * 4 + part) * C_ + f] = b1x;
    smem[(2 * 4 + part) * C_ + f] = b1y;
    smem[(3 * 4 + part) * C_ + f] = b1z;
    smem[(4 * 4 + part) * C_ + f] = a1x;
    smem[(5 * 4 + part) * C_ + f] = a1y;
    smem[(6 * 4 + part) * C_ + f] = a1z;
    smem[(7 * 4 + part) * C_ + f] = o0;
    smem[(8 * 4 + part) * C_ + f] = o1x;
    smem[(9 * 4 + part) * C_ + f] = o1y;
    smem[(10 * 4 + part) * C_ + f] = o1z;
    __syncthreads();

    {   // reduce 11*128 = 1408 elements -> compact s[k][c] = smem[k*C_+c]
        const int i0 = tid, i1 = tid + 512, i2 = tid + 1024;
        const bool has2 = i2 < 11 * C_;
        float r0, r1, r2 = 0.f;
        {
            const int k = i0 >> 7, c = i0 & 127;
            r0 = smem[(k * 4 + 0) * C_ + c] + smem[(k * 4 + 1) * C_ + c]
               + smem[(k * 4 + 2) * C_ + c] + smem[(k * 4 + 3) * C_ + c];
        }
        {
            const int k = i1 >> 7, c = i1 & 127;
            r1 = smem[(k * 4 + 0) * C_ + c] + smem[(k * 4 + 1) * C_ + c]
               + smem[(k * 4 + 2) * C_ + c] + smem[(k * 4 + 3) * C_ + c];
        }
        if (has2) {
            const int k = i2 >> 7, c = i2 & 127;
            r2 = smem[(k * 4 + 0) * C_ + c] + smem[(k * 4 + 1) * C_ + c]
               + smem[(k * 4 + 2) * C_ + c] + smem[(k * 4 + 3) * C_ + c];
        }
        __syncthreads();
        smem[i0] = r0;
        smem[i1] = r1;
        if (has2) smem[i2] = r2;
    }
    __syncthreads();

    {   // SI: j = tid>>7; j=0 -> y0 (w0, s0/s7), j=1..3 -> y_j (w1, s_j/s_{3+j}/s_{7+j})
        const int j = tid >> 7;
        float y;
        if (j == 0) {
            y = b0v[f];
            const float4* w = (const float4*)(w0 + (size_t)f * (2 * C_));
            const float* s0 = smem + 0 * C_;
            const float* s7 = smem + 7 * C_;
            for (int c4 = 0; c4 < C_ / 4; ++c4) {
                const float4 wa = w[c4];
                const float4 wb = w[C_ / 4 + c4];
                y = fmaf(wa.x, s0[c4 * 4 + 0], y);
                y = fmaf(wa.y, s0[c4 * 4 + 1], y);
                y = fmaf(wa.z, s0[c4 * 4 + 2], y);
                y = fmaf(wa.w, s0[c4 * 4 + 3], y);
                y = fmaf(wb.x, s7[c4 * 4 + 0], y);
                y = fmaf(wb.y, s7[c4 * 4 + 1], y);
                y = fmaf(wb.z, s7[c4 * 4 + 2], y);
                y = fmaf(wb.w, s7[c4 * 4 + 3], y);
            }
        } else {
            y = 0.f;
            const float4* w = (const float4*)(w1 + (size_t)f * (3 * C_));
            const float* sb = smem + j * C_;
            const float* sa = smem + (3 + j) * C_;
            const float* so = smem + (7 + j) * C_;
            for (int c4 = 0; c4 < C_ / 4; ++c4) {
                const float4 w_b = w[c4];
                const float4 w_a = w[C_ / 4 + c4];
                const float4 w_o = w[2 * (C_ / 4) + c4];
                y = fmaf(w_b.x, sb[c4 * 4 + 0], y);
                y = fmaf(w_b.y, sb[c4 * 4 + 1], y);
                y = fmaf(w_b.z, sb[c4 * 4 + 2], y);
                y = fmaf(w_b.w, sb[c4 * 4 + 3], y);
                y = fmaf(w_a.x, sa[c4 * 4 + 0], y);
                y = fmaf(w_a.y, sa[c4 * 4 + 1], y);
                y = fmaf(w_a.z, sa[c4 * 4 + 2], y);
                y = fmaf(w_a.w, sa[c4 * 4 + 3], y);
                y = fmaf(w_o.x, so[c4 * 4 + 0], y);
                y = fmaf(w_o.y, so[c4 * 4 + 1], y);
                y = fmaf(w_o.z, so[c4 * 4 + 2], y);
                y = fmaf(w_o.w, so[c4 * 4 + 3], y);
            }
        }
        ys[j * C_ + f] = y;
    }
    __syncthreads();

    if (NONLIN) {
        if (tid < C_) {
            const float y0 = ys[tid];
            const float yx = ys[C_ + tid], yy = ys[2 * C_ + tid], yz = ys[3 * C_ + tid];
            const float x0v = y0 > 0.f ? y0 : expm1f(y0);
            const float nsq = fmaf(yx, yx, fmaf(yy, yy, yz * yz));
            const float nn  = sqrtf(fmaxf(nsq, 1e-12f));
            const float g   = nlb[tid] + nn;
            const float sc  = (g > 0.f ? g : expm1f(g)) / nn;
            float* xo = xout + (size_t)a * 4 * C_ + tid;
            xo[0 * C_] = x0v;
            xo[1 * C_] = yx * sc;
            xo[2 * C_] = yy * sc;
            xo[3 * C_] = yz * sc;
        }
    }
    if (LAST) {
        if (tid < C_) {
            const float y0 = ys[tid];
            const float yx = ys[C_ + tid], yy = ys[2 * C_ + tid], yz = ys[3 * C_ + tid];
            out[a * C_ + tid] = y0;                   // x0 [N,C,1]
            float* o1 = out + N_ * C_;                // x1 [N,C,3]
            o1[a * (C_ * 3) + tid * 3 + 0] = yx;
            o1[a * (C_ * 3) + tid * 3 + 1] = yy;
            o1[a * (C_ * 3) + tid * 3 + 2] = yz;
        }
        __syncthreads();
        if (tid < 8) {                                // atom head from ys[0..127]
            float acc = predb[tid];
            for (int c = 0; c < C_; ++c)
                acc = fmaf(predW[tid * C_ + c], ys[c], acc);
            out[N_ * C_ + N_ * C_ * 3 + a * 8 + tid] = acc;
        }
    }
}

// ---------------------------------------------------------------------------
extern "C" void kernel_launch(void* const* d_in, const int* in_sizes, int n_in,
                              void* d_out, int out_size, void* d_ws, size_t ws_size,
                              hipStream_t stream)
{
    const float* r       = (const float*)d_in[0];
    const float* onehot  = (const float*)d_in[1];
    const float* embed_W = (const float*)d_in[2];
    const float* embed_b = (const float*)d_in[3];
    const float* Rw1     = (const float*)d_in[4];
    const float* Rb1     = (const float*)d_in[5];
    const float* Rw2     = (const float*)d_in[6];
    const float* Rb2     = (const float*)d_in[7];
    const float* si0_w0  = (const float*)d_in[8];
    const float* si0_b0  = (const float*)d_in[9];
    const float* si0_w1  = (const float*)d_in[10];
    const float* si1_w0  = (const float*)d_in[11];
    const float* si1_b0  = (const float*)d_in[12];
    const float* si1_w1  = (const float*)d_in[13];
    const float* si2_w0  = (const float*)d_in[14];
    const float* si2_b0  = (const float*)d_in[15];
    const float* si2_w1  = (const float*)d_in[16];
    const float* nl_b0   = (const float*)d_in[17];
    const float* nl_b1   = (const float*)d_in[18];
    const float* pred_W  = (const float*)d_in[19];
    const float* pred_b  = (const float*)d_in[20];
    (void)in_sizes; (void)n_in; (void)out_size; (void)ws_size;

    const float delta     = DMAX_ / (float)(M_ - 1);
    const float inv_delta = (float)(M_ - 1) / DMAX_;

    char* wsb = (char*)d_ws;
    __half2* table = (__half2*)wsb;                                   // M*12*C half2
    float*   e     = (float*)(wsb + (size_t)M_ * 12 * C_ * sizeof(__half2));
    float*   xa    = e + (size_t)N_ * C_;                             // [N][4][C]
    float*   xb    = xa + (size_t)N_ * 4 * C_;                        // [N][4][C]

    float* out = (float*)d_out;

    build_table_kernel<<<M_ / 4, 256, 0, stream>>>(Rw1, Rb1, Rw2, Rb2, table, delta);
    embed_kernel<<<(N_ * C_) / 256, 256, 0, stream>>>(onehot, embed_W, embed_b, e);
    layer0_kernel<<<N_, 512, 0, stream>>>(r, e, table, inv_delta,
                                          si0_w0, si0_b0, si0_w1, nl_b0, xa);
    full_layer_kernel<true, false, 2><<<N_, 512, 0, stream>>>(
        r, xa, table, inv_delta, si1_w0, si1_b0, si1_w1, nl_b1,
        xb, nullptr, nullptr, nullptr);
    full_layer_kernel<false, true, 7><<<N_, 512, 0, stream>>>(
        r, xb, table, inv_delta, si2_w0, si2_b0, si2_w1, nullptr,
        nullptr, out, pred_W, pred_b);
}